// Round 4
// baseline (355.603 us; speedup 1.0000x reference)
//
#include <hip/hip_runtime.h>

// Problem constants: B=1, C=32, H=96, W=192, max_disp=192 → D=64
// Output: (1, 2C, D, H, W) fp32, 302 MB pure-write stream.
//   ch <  C : out = x[ch][h][w]      * (w >= d)
//   ch >= C : out = y[ch-C][h][w-d]  * (w >= d)
//
// R4 theory: fill kernel hits 6.35 TB/s, we hit ~2.7. Order/occupancy/nt all
// A/B'd neutral. Remaining difference: our stores carried load dependencies
// (R0: 16 serially-dependent scalar loads per thread). This version hoists ALL
// loads before the store loop: y-branch preloads the entire 20-float sliding
// window with 5 aligned f4 loads, store loop is pure register traffic.
//
// DIAGNOSTIC (this round only): kernel launched TWICE (idempotent pure-write)
// so dur_us = F + 2K pins our kernel's true duration K against the ~190 µs
// harness fill F that dominates the top-5 dispatch table.
constexpr int C      = 32;
constexpr int D      = 64;    // max_disp / 3
constexpr int H      = 96;
constexpr int W      = 192;
constexpr int W4     = W / 4;      // 48
constexpr int DCHUNK = 16;         // d-values per thread
constexpr int NCHUNK = D / DCHUNK; // 4

typedef float f4 __attribute__((ext_vector_type(4)));

__global__ __launch_bounds__(256) void fusion_kernel(const float* __restrict__ x,
                                                     const float* __restrict__ y,
                                                     float* __restrict__ out) {
    const int tid  = blockIdx.x * blockDim.x + threadIdx.x;
    const int w4   = tid % W4;
    int rest       = tid / W4;
    const int h    = rest % H;
    rest          /= H;
    const int ch   = rest % (2 * C);
    const int d0   = (rest / (2 * C)) * DCHUNK;   // chunk base (multiple of 16)
    const int w    = w4 * 4;

    int outoff = (ch * D + d0) * (H * W) + h * W + w;

    if (ch < C) {
        // one aligned vec4 load, then 16 masked stores — no loads in loop
        const f4 xv = *(const f4*)(&x[(ch * H + h) * W + w]);
        #pragma unroll
        for (int i = 0; i < DCHUNK; ++i) {
            const int d = d0 + i;
            f4 v = xv;
            if (w + 0 < d) v.x = 0.f;
            if (w + 1 < d) v.y = 0.f;
            if (w + 2 < d) v.z = 0.f;
            if (w + 3 < d) v.w = 0.f;
            *(f4*)(&out[outoff + i * (H * W)]) = v;
        }
    } else {
        // Preload full sliding window y_row[w-d0-16 .. w-d0+3] (20 floats) with
        // 5 ALIGNED f4 loads (w ≡ 0 mod 4, d0 ≡ 0 mod 16 → base ≡ 0 mod 4).
        // Underflow (only possible at plane 0 / row 0) clamps to y[0]; every
        // clamped component is provably masked (unmasked ⇔ w+c ≥ d ⇔ in-row
        // index ≥ 0), so garbage there is harmless.
        const int rowbase = ((ch - C) * H + h) * W;   // float index of row start
        const int g0      = rowbase + (w - d0 - 16);  // window start (mult. of 4)
        float r[20];
        #pragma unroll
        for (int t = 0; t < 5; ++t) {
            const f4 rv = *(const f4*)(&y[max(g0 + 4 * t, 0)]);
            r[4 * t + 0] = rv.x;
            r[4 * t + 1] = rv.y;
            r[4 * t + 2] = rv.z;
            r[4 * t + 3] = rv.w;
        }
        // r[k] = y_row[w - d0 - 16 + k]; output comp c at d=d0+i is r[c - i + 16]
        #pragma unroll
        for (int i = 0; i < DCHUNK; ++i) {
            const int d = d0 + i;
            f4 s;
            s.x = r[16 - i];
            s.y = r[17 - i];
            s.z = r[18 - i];
            s.w = r[19 - i];
            if (w + 0 < d) s.x = 0.f;
            if (w + 1 < d) s.y = 0.f;
            if (w + 2 < d) s.z = 0.f;
            if (w + 3 < d) s.w = 0.f;
            *(f4*)(&out[outoff + i * (H * W)]) = s;
        }
    }
}

extern "C" void kernel_launch(void* const* d_in, const int* in_sizes, int n_in,
                              void* d_out, int out_size, void* d_ws, size_t ws_size,
                              hipStream_t stream) {
    const float* x = (const float*)d_in[0];
    const float* y = (const float*)d_in[1];
    float* out     = (float*)d_out;

    constexpr int total  = 2 * C * H * W4 * NCHUNK;   // 1,179,648 threads
    constexpr int block  = 256;
    constexpr int grid   = total / block;             // 4608 blocks
    // Double launch — diagnostic decomposition (see header comment). The
    // kernel is a pure idempotent write, so correctness is unaffected.
    fusion_kernel<<<grid, block, 0, stream>>>(x, y, out);
    fusion_kernel<<<grid, block, 0, stream>>>(x, y, out);
}

// Round 6
// 311.382 us; speedup vs baseline: 1.1420x; 1.1420x over previous
//
#include <hip/hip_runtime.h>

// Problem constants: B=1, C=32, H=96, W=192, max_disp=192 → D=64
// Output: (1, 2C, D, H, W) fp32, 302 MB pure-write stream.
//   ch <  C : out = x[ch][h][w]      * (w >= d)
//   ch >= C : out = y[ch-C][h][w-d]  * (w >= d)
//
// R5: store-stream restructure. R4's decomposition (double-launch) pinned our
// kernel at K≈79 µs (3.8 TB/s) vs the fill's 6.1 TB/s. Remaining structural
// difference: R0/R4 waves stride stores 72 KB apart (16 d-planes) → 16
// scattered DRAM page streams per wave + channel camping (72 KB = 288×256 B).
// This version fixes (ch,d) per thread and iterates h: each wave's 16 store
// instructions form 2 sequential 12 KB streams (segments advance 768 B/iter).
// y loads move back into the loop but are INDEPENDENT (one per row); a
// two-pass fully-unrolled body (loads first, then mask+store) keeps them all
// in flight before the store burst. Masks are thread-invariant (w,d fixed).
constexpr int C     = 32;
constexpr int D     = 64;    // max_disp / 3
constexpr int H     = 96;
constexpr int W     = 192;
constexpr int W4    = W / 4;   // 48
constexpr int HB    = 6;       // h-blocks
constexpr int HITER = 16;      // rows per thread (HB*HITER = H)

typedef float f4  __attribute__((ext_vector_type(4)));
typedef float f4u __attribute__((ext_vector_type(4), aligned(4))); // dword-aligned dwordx4 (proven on gfx950 in R3)

__global__ __launch_bounds__(256) void fusion_kernel(const float* __restrict__ x,
                                                     const float* __restrict__ y,
                                                     float* __restrict__ out) {
    const int tid = blockIdx.x * blockDim.x + threadIdx.x;
    const int w4  = tid % W4;
    int rest      = tid / W4;
    const int hb  = rest % HB;
    rest         /= HB;
    const int d   = rest % D;
    const int ch  = rest / D;        // [0, 2C)
    const int w   = w4 * 4;
    const int h0  = hb * HITER;

    // out element offset of (ch, d, h0, w); iteration i adds i*W (768 B)
    const int outoff = (ch * D + d) * (H * W) + h0 * W + w;

    // thread-invariant mask (w, d fixed): component c zeroed iff w+c < d
    const bool m0 = (w + 0) < d;
    const bool m1 = (w + 1) < d;
    const bool m2 = (w + 2) < d;
    const bool m3 = (w + 3) < d;

    f4 v[HITER];   // fully-unrolled static indexing only → stays in VGPRs

    if (ch < C) {
        const float* xr = x + ch * (H * W) + h0 * W + w;   // aligned
        #pragma unroll
        for (int i = 0; i < HITER; ++i)
            v[i] = *(const f4*)(xr + i * W);
    } else {
        // row h0+i, shifted by d: off = off0 + i*W. off0 ≥ -63 and grows by
        // 192/iter → only i=0 can be negative (ch'=0, h0=0, w<d).
        const int off0 = (ch - C) * (H * W) + h0 * W + w - d;
        if (off0 >= 0) {
            v[0] = *(const f4u*)(y + off0);
        } else {
            // rare: first row of y, left edge. Clamped comps are masked
            // (unmasked ⇔ w+c ≥ d ⇔ off0+c ≥ 0 → exact load).
            v[0].x = y[max(off0 + 0, 0)];
            v[0].y = y[max(off0 + 1, 0)];
            v[0].z = y[max(off0 + 2, 0)];
            v[0].w = y[max(off0 + 3, 0)];
        }
        #pragma unroll
        for (int i = 1; i < HITER; ++i)
            v[i] = *(const f4u*)(y + off0 + i * W);
    }

    // mask + store burst: 2 sequential streams per wave (768 B + 256 B
    // segments advancing one row per iteration)
    #pragma unroll
    for (int i = 0; i < HITER; ++i) {
        f4 s = v[i];
        if (m0) s.x = 0.f;
        if (m1) s.y = 0.f;
        if (m2) s.z = 0.f;
        if (m3) s.w = 0.f;
        *(f4*)(out + outoff + i * W) = s;
    }
}

extern "C" void kernel_launch(void* const* d_in, const int* in_sizes, int n_in,
                              void* d_out, int out_size, void* d_ws, size_t ws_size,
                              hipStream_t stream) {
    const float* x = (const float*)d_in[0];
    const float* y = (const float*)d_in[1];
    float* out     = (float*)d_out;

    constexpr int total = 2 * C * D * HB * W4;   // 1,179,648 threads
    constexpr int block = 256;
    constexpr int grid  = total / block;         // 4608 blocks
    fusion_kernel<<<grid, block, 0, stream>>>(x, y, out);
}

// Round 7
// 301.833 us; speedup vs baseline: 1.1781x; 1.0316x over previous
//
#include <hip/hip_runtime.h>

// Problem constants: B=1, C=32, H=96, W=192, max_disp=192 → D=64
// Output: (1, 2C, D, H, W) fp32, 302 MB pure-write stream.
//   ch <  C : out = x[ch][h][w]      * (w >= d)
//   ch >= C : out = y[ch-C][h][w-d]  * (w >= d)
//
// R6: linear store order + fully hoisted loads — the untested cell of the
// (order × hoisting) matrix. K extracted by fill-subtraction across rounds:
//   d-strided+dep=107 (R2) | d-strided+hoist=79 (R4) | linear+dep=132 (R3)
// The harness fill (linear, no loads) sustains 6.1 TB/s; this cell matches
// its pattern exactly.
//
// Key structure: grid-stride = 1,179,648 f4 = exactly 256 (ch,d)-planes.
// Therefore each thread's 16 iterations have FIXED (h,w,d) and ch stepping by
// 4: iterations 0-7 are always x-branch, 8-15 always y-branch. Masks are
// thread-invariant; all 16 loads are independent and issued before the
// 16-store burst; every wave-store is 1 KB contiguous and the grid sweeps 16
// contiguous 18.9 MB fronts in ascending address order.
constexpr int C      = 32;
constexpr int D      = 64;            // max_disp / 3
constexpr int H      = 96;
constexpr int W      = 192;
constexpr int HW     = H * W;         // 18432 floats per plane
constexpr int PLANE4 = HW / 4;        // 4608 f4 per plane
constexpr int NTH    = 2 * C * D * PLANE4 / 16;   // 1,179,648 threads (16 f4 each)

typedef float f4  __attribute__((ext_vector_type(4)));
typedef float f4u __attribute__((ext_vector_type(4), aligned(4))); // dword-aligned dwordx4 (validated R3/R5)

__global__ __launch_bounds__(256) void fusion_kernel(const float* __restrict__ x,
                                                     const float* __restrict__ y,
                                                     float* __restrict__ out) {
    const int tid    = blockIdx.x * blockDim.x + threadIdx.x;  // f4 index, iter 0
    const int plane0 = tid / PLANE4;          // [0,256), wave-uniform (4608 = 72 waves)
    const int rem    = tid - plane0 * PLANE4; // [0,4608) = h*48 + w4
    const int d      = plane0 & 63;
    const int ch0    = plane0 >> 6;           // [0,4)
    const int w      = (rem % 48) * 4;

    // thread-invariant mask: component c zeroed iff w+c < d
    const bool m0 = (w + 0) < d;
    const bool m1 = (w + 1) < d;
    const bool m2 = (w + 2) < d;
    const bool m3 = (w + 3) < d;

    const int xoff0 = ch0 * HW + rem * 4;     // x float idx, iter 0 (aligned)
    const int yoff0 = xoff0 - d;              // y float idx, iter 8 (unaligned)

    f4 v[16];   // fully-unrolled static indexing only → stays in VGPRs

    // x-branch loads: iterations 0..7, ch = ch0 + 4i  → offset step 4*HW
    #pragma unroll
    for (int i = 0; i < 8; ++i)
        v[i] = *(const f4*)(x + xoff0 + i * (4 * HW));

    // y-branch loads: iterations 8..15, ch-C = ch0 + 4(i-8), shifted by d.
    // Only the first can underflow (yoff0 ≥ -63, +4*HW per step). Clamped
    // components are provably masked (unmasked ⇔ w+c ≥ d ⇔ yoff0+c ≥ 0).
    if (yoff0 >= 0) {
        v[8] = *(const f4u*)(y + yoff0);
    } else {
        v[8].x = y[max(yoff0 + 0, 0)];
        v[8].y = y[max(yoff0 + 1, 0)];
        v[8].z = y[max(yoff0 + 2, 0)];
        v[8].w = y[max(yoff0 + 3, 0)];
    }
    #pragma unroll
    for (int i = 1; i < 8; ++i)
        v[8 + i] = *(const f4u*)(y + yoff0 + i * (4 * HW));

    // pure store burst: ascending addresses, 1 KB contiguous per wave-store,
    // grid-wide contiguous 18.9 MB front per iteration
    #pragma unroll
    for (int i = 0; i < 16; ++i) {
        f4 s = v[i];
        if (m0) s.x = 0.f;
        if (m1) s.y = 0.f;
        if (m2) s.z = 0.f;
        if (m3) s.w = 0.f;
        *(f4*)(out + (tid + i * NTH) * 4) = s;   // max idx 75.5M-4, fits int
    }
}

extern "C" void kernel_launch(void* const* d_in, const int* in_sizes, int n_in,
                              void* d_out, int out_size, void* d_ws, size_t ws_size,
                              hipStream_t stream) {
    const float* x = (const float*)d_in[0];
    const float* y = (const float*)d_in[1];
    float* out     = (float*)d_out;

    constexpr int block = 256;
    constexpr int grid  = NTH / block;   // 4608 blocks
    fusion_kernel<<<grid, block, 0, stream>>>(x, y, out);
}

// Round 10
// 301.214 us; speedup vs baseline: 1.1806x; 1.0021x over previous
//
#include <hip/hip_runtime.h>

// Problem constants: B=1, C=32, H=96, W=192, max_disp=192 → D=64
// Output: (1, 2C, D, H, W) fp32, 302 MB pure-write stream.
//   ch <  C : out = x[ch][h][w]      * (w >= d)
//   ch >= C : out = y[ch-C][h][w-d]  * (w >= d)
//
// R7/R8/R9: R4's kernel (d-plane-strided stores + fully hoisted window loads),
// SINGLE launch. R4's double-launch K≈79 µs may be biased low (2nd instance
// re-writes LLC-resident lines → in-window HBM drain partially skipped).
// This run disambiguates: ~275 µs total confirms d-strided+hoisted at K≈79;
// ~300 µs means the LLC bias was real and store order is irrelevant.
// (R8/R9 = unchanged resubmissions after broker-side container failures.)
constexpr int C      = 32;
constexpr int D      = 64;    // max_disp / 3
constexpr int H      = 96;
constexpr int W      = 192;
constexpr int W4     = W / 4;      // 48
constexpr int DCHUNK = 16;         // d-values per thread
constexpr int NCHUNK = D / DCHUNK; // 4

typedef float f4 __attribute__((ext_vector_type(4)));

__global__ __launch_bounds__(256) void fusion_kernel(const float* __restrict__ x,
                                                     const float* __restrict__ y,
                                                     float* __restrict__ out) {
    const int tid  = blockIdx.x * blockDim.x + threadIdx.x;
    const int w4   = tid % W4;
    int rest       = tid / W4;
    const int h    = rest % H;
    rest          /= H;
    const int ch   = rest % (2 * C);
    const int d0   = (rest / (2 * C)) * DCHUNK;   // chunk base (multiple of 16)
    const int w    = w4 * 4;

    int outoff = (ch * D + d0) * (H * W) + h * W + w;

    if (ch < C) {
        // one aligned vec4 load, then 16 masked stores — no loads in loop
        const f4 xv = *(const f4*)(&x[(ch * H + h) * W + w]);
        #pragma unroll
        for (int i = 0; i < DCHUNK; ++i) {
            const int d = d0 + i;
            f4 v = xv;
            if (w + 0 < d) v.x = 0.f;
            if (w + 1 < d) v.y = 0.f;
            if (w + 2 < d) v.z = 0.f;
            if (w + 3 < d) v.w = 0.f;
            *(f4*)(&out[outoff + i * (H * W)]) = v;
        }
    } else {
        // Preload full sliding window y_row[w-d0-16 .. w-d0+3] (20 floats) with
        // 5 ALIGNED f4 loads (w ≡ 0 mod 4, d0 ≡ 0 mod 16 → base ≡ 0 mod 4).
        // Underflow (only plane 0 / row 0) clamps to y[0]; every clamped
        // component is provably masked (unmasked ⇔ w+c ≥ d ⇔ in-row idx ≥ 0).
        const int rowbase = ((ch - C) * H + h) * W;   // float index of row start
        const int g0      = rowbase + (w - d0 - 16);  // window start (mult. of 4)
        float r[20];
        #pragma unroll
        for (int t = 0; t < 5; ++t) {
            const f4 rv = *(const f4*)(&y[max(g0 + 4 * t, 0)]);
            r[4 * t + 0] = rv.x;
            r[4 * t + 1] = rv.y;
            r[4 * t + 2] = rv.z;
            r[4 * t + 3] = rv.w;
        }
        // r[k] = y_row[w - d0 - 16 + k]; output comp c at d=d0+i is r[c - i + 16]
        #pragma unroll
        for (int i = 0; i < DCHUNK; ++i) {
            const int d = d0 + i;
            f4 s;
            s.x = r[16 - i];
            s.y = r[17 - i];
            s.z = r[18 - i];
            s.w = r[19 - i];
            if (w + 0 < d) s.x = 0.f;
            if (w + 1 < d) s.y = 0.f;
            if (w + 2 < d) s.z = 0.f;
            if (w + 3 < d) s.w = 0.f;
            *(f4*)(&out[outoff + i * (H * W)]) = s;
        }
    }
}

extern "C" void kernel_launch(void* const* d_in, const int* in_sizes, int n_in,
                              void* d_out, int out_size, void* d_ws, size_t ws_size,
                              hipStream_t stream) {
    const float* x = (const float*)d_in[0];
    const float* y = (const float*)d_in[1];
    float* out     = (float*)d_out;

    constexpr int total  = 2 * C * H * W4 * NCHUNK;   // 1,179,648 threads
    constexpr int block  = 256;
    constexpr int grid   = total / block;             // 4608 blocks
    fusion_kernel<<<grid, block, 0, stream>>>(x, y, out);
}